// Round 6
// baseline (637.768 us; speedup 1.0000x reference)
//
#include <hip/hip_runtime.h>
#include <hip/hip_bf16.h>
#include <math.h>

#define N_NODES 100000
#define N_EDGES 1600000
#define F_IN 15
#define H1 64
#define H2 32
#define BN_EPS 1e-5f
#define NBLK 2048            // grid-stride blocks for the layer kernels
#define RELU1(v) fmaxf(fmaf((v), scale, shift), 0.f)

// bf16 storage helpers (RNE)
__device__ __forceinline__ unsigned short f2bf(float f) {
    unsigned u = __float_as_uint(f);
    u += 0x7FFFu + ((u >> 16) & 1u);
    return (unsigned short)(u >> 16);
}
__device__ __forceinline__ float bf2f(unsigned short h) {
    return __uint_as_float(((unsigned)h) << 16);
}

// ---------------- CSR build ----------------

__global__ void k_deg(const int* __restrict__ dst, int* __restrict__ deg) {
    int e = blockIdx.x * blockDim.x + threadIdx.x;
    if (e < N_EDGES) atomicAdd(&deg[dst[e]], 1);
}

__global__ void k_scan_a(const int* __restrict__ deg, int* __restrict__ off,
                         int* __restrict__ part) {
    __shared__ int s[1024];
    int i = blockIdx.x * 1024 + threadIdx.x;
    int v = (i < N_NODES) ? deg[i] : 0;
    s[threadIdx.x] = v;
    __syncthreads();
    for (int o = 1; o < 1024; o <<= 1) {
        int t = (threadIdx.x >= o) ? s[threadIdx.x - o] : 0;
        __syncthreads();
        s[threadIdx.x] += t;
        __syncthreads();
    }
    if (i < N_NODES) off[i] = s[threadIdx.x] - v;   // block-local exclusive
    if (threadIdx.x == 1023) part[blockIdx.x] = s[1023];
}

__global__ void k_scan_b(int* __restrict__ part, int nb) {
    __shared__ int s[128];
    int v = (threadIdx.x < nb) ? part[threadIdx.x] : 0;
    s[threadIdx.x] = v;
    __syncthreads();
    for (int o = 1; o < 128; o <<= 1) {
        int t = (threadIdx.x >= o) ? s[threadIdx.x - o] : 0;
        __syncthreads();
        s[threadIdx.x] += t;
        __syncthreads();
    }
    if (threadIdx.x < nb) part[threadIdx.x] = s[threadIdx.x] - v;  // exclusive base
}

__global__ void k_scan_c(int* __restrict__ off, int* __restrict__ cur,
                         const int* __restrict__ part) {
    int i = blockIdx.x * blockDim.x + threadIdx.x;
    if (i < N_NODES) {
        int v = off[i] + part[i >> 10];
        off[i] = v;
        cur[i] = v;
    }
    if (i == 0) off[N_NODES] = N_EDGES;
}

__global__ void k_fill(const int* __restrict__ src, const int* __restrict__ dst,
                       int* __restrict__ cur, int* __restrict__ srt) {
    int e = blockIdx.x * blockDim.x + threadIdx.x;
    if (e < N_EDGES) {
        int p = atomicAdd(&cur[dst[e]], 1);
        srt[p] = src[e];
    }
}

// ---------------- Layer 1: wave-per-node, d=15 -> 64 ----------------
// Batch-16 gather (1 coalesced idx load + shfl broadcast); LDS staging of
// mean/own (same-wave, HW-validated); register weight rows; bf16 h1 out.

__launch_bounds__(256)
__global__ void k_l1(const float* __restrict__ x, const int* __restrict__ off,
                     const int* __restrict__ srt,
                     const float* __restrict__ W1l, const float* __restrict__ b1l,
                     const float* __restrict__ W1r,
                     unsigned short* __restrict__ h1b, float* __restrict__ stats) {
    __shared__ float m_lds[4][16], o_lds[4][16];
    __shared__ float sred[2 * H1];
    int lane = threadIdx.x & 63;
    int w = threadIdx.x >> 6;
    int gw = blockIdx.x * 4 + w;
    const int NW = NBLK * 4;

    float wl[F_IN], wr[F_IN];
#pragma unroll
    for (int k = 0; k < F_IN; ++k) {
        wl[k] = W1l[lane * F_IN + k];
        wr[k] = W1r[lane * F_IN + k];
    }
    float bj = b1l[lane];

    if (threadIdx.x < 2 * H1) sred[threadIdx.x] = 0.f;
    __syncthreads();

    float sS = 0.f, sQ = 0.f;
    for (int n = gw; n < N_NODES; n += NW) {
        int o0 = off[n], o1 = off[n + 1];
        float sum = 0.f;
        int i = o0;
        for (; i + 16 <= o1; i += 16) {
            int my = (lane < 16) ? srt[i + lane] : 0;
            float v[16];
#pragma unroll
            for (int b = 0; b < 16; ++b) {
                int s = __shfl(my, b, 64);
                v[b] = (lane < F_IN) ? x[(long)s * F_IN + lane] : 0.f;
            }
#pragma unroll
            for (int b = 0; b < 16; ++b) sum += v[b];
        }
        for (; i + 8 <= o1; i += 8) {
            int my = (lane < 8) ? srt[i + lane] : 0;
            float v[8];
#pragma unroll
            for (int b = 0; b < 8; ++b) {
                int s = __shfl(my, b, 64);
                v[b] = (lane < F_IN) ? x[(long)s * F_IN + lane] : 0.f;
            }
#pragma unroll
            for (int b = 0; b < 8; ++b) sum += v[b];
        }
        for (; i < o1; ++i) {
            int s = srt[i];
            if (lane < F_IN) sum += x[(long)s * F_IN + lane];
        }
        float inv = 1.f / (float)max(o1 - o0, 1);
        if (lane < F_IN) {
            m_lds[w][lane] = sum * inv;
            o_lds[w][lane] = x[(long)n * F_IN + lane];
        }
        // same-wave LDS write->read (HW-validated pattern)
        float acc = bj;
#pragma unroll
        for (int k = 0; k < F_IN; ++k)
            acc += m_lds[w][k] * wl[k] + o_lds[w][k] * wr[k];
        h1b[(long)n * H1 + lane] = f2bf(acc);
        sS += acc; sQ += acc * acc;   // fp32 stats (pre-rounding)
    }
    atomicAdd(&sred[lane], sS);
    atomicAdd(&sred[H1 + lane], sQ);
    __syncthreads();
    if (threadIdx.x < 2 * H1) atomicAdd(&stats[threadIdx.x], sred[threadIdx.x]);
}

// ---------------- Layer 2: wave-per-node, d=64 -> 32 ----------------
// bf16 h1 gather (batch-16), lazy BN1+ReLU; weights in padded LDS
// (bank=(lane+k)%32, 2-way = free); bf16 h2 out.

__launch_bounds__(256)
__global__ void k_l2(const unsigned short* __restrict__ h1b, const int* __restrict__ off,
                     const int* __restrict__ srt,
                     const float* __restrict__ W2l, const float* __restrict__ b2l,
                     const float* __restrict__ W2r,
                     const float* __restrict__ g1, const float* __restrict__ beta1,
                     const float* __restrict__ stats1,
                     unsigned short* __restrict__ h2b, float* __restrict__ stats2) {
    __shared__ float wlds[H1][H1 + 1];
    __shared__ float meanb[4][H1], ownb[4][H1];
    __shared__ float sred[2 * H2];
    int lane = threadIdx.x & 63;
    int w = threadIdx.x >> 6;
    int gw = blockIdx.x * 4 + w;
    const int NW = NBLK * 4;

    float mu = stats1[lane] * (1.f / N_NODES);
    float var = stats1[H1 + lane] * (1.f / N_NODES) - mu * mu;
    float scale = rsqrtf(var + BN_EPS) * g1[lane];
    float shift = beta1[lane] - mu * scale;

    // row j of wlds = W2l[j][*] (j<32) or W2r[j-32][*] (j>=32)
    for (int idx = threadIdx.x; idx < H1 * H1; idx += 256) {
        int jj = idx >> 6, kk = idx & 63;
        wlds[jj][kk] = (jj < H2) ? W2l[jj * H1 + kk] : W2r[(jj - H2) * H1 + kk];
    }
    float bj = (lane < H2) ? b2l[lane] : 0.f;
    if (threadIdx.x < 2 * H2) sred[threadIdx.x] = 0.f;
    __syncthreads();

    float sS = 0.f, sQ = 0.f;
    for (int n = gw; n < N_NODES; n += NW) {
        int o0 = off[n], o1 = off[n + 1];
        float sum = 0.f;
        int i = o0;
        for (; i + 16 <= o1; i += 16) {
            int my = (lane < 16) ? srt[i + lane] : 0;
            float v[16];
#pragma unroll
            for (int b = 0; b < 16; ++b) {
                int s = __shfl(my, b, 64);
                v[b] = bf2f(h1b[(long)s * H1 + lane]);
            }
#pragma unroll
            for (int b = 0; b < 16; ++b) sum += RELU1(v[b]);
        }
        for (; i + 8 <= o1; i += 8) {
            int my = (lane < 8) ? srt[i + lane] : 0;
            float v[8];
#pragma unroll
            for (int b = 0; b < 8; ++b) {
                int s = __shfl(my, b, 64);
                v[b] = bf2f(h1b[(long)s * H1 + lane]);
            }
#pragma unroll
            for (int b = 0; b < 8; ++b) sum += RELU1(v[b]);
        }
        for (; i < o1; ++i) {
            int s = srt[i];
            sum += RELU1(bf2f(h1b[(long)s * H1 + lane]));
        }
        float inv = 1.f / (float)max(o1 - o0, 1);
        meanb[w][lane] = sum * inv;
        ownb[w][lane] = RELU1(bf2f(h1b[(long)n * H1 + lane]));

        const float* bsel = (lane < H2) ? &meanb[w][0] : &ownb[w][0];
        float acc = bj;
#pragma unroll
        for (int k = 0; k < H1; ++k) acc += bsel[k] * wlds[lane][k];
        float other = __shfl_xor(acc, 32, 64);
        if (lane < H2) {
            float hp = acc + other;
            h2b[(long)n * H2 + lane] = f2bf(hp);
            sS += hp; sQ += hp * hp;   // fp32 stats
        }
    }
    if (lane < H2) {
        atomicAdd(&sred[lane], sS);
        atomicAdd(&sred[H2 + lane], sQ);
    }
    __syncthreads();
    if (threadIdx.x < 2 * H2) atomicAdd(&stats2[threadIdx.x], sred[threadIdx.x]);
}

// ---------------- Layer 3: 2 nodes per wave, d=32 -> 2, log_softmax ----------------

__launch_bounds__(256)
__global__ void k_l3(const unsigned short* __restrict__ h2b, const int* __restrict__ off,
                     const int* __restrict__ srt,
                     const float* __restrict__ W3l, const float* __restrict__ b3l,
                     const float* __restrict__ W3r,
                     const float* __restrict__ g2, const float* __restrict__ beta2,
                     const float* __restrict__ stats2, float* __restrict__ out) {
    int lane = threadIdx.x & 63;
    int w = threadIdx.x >> 6;
    int h = lane >> 5;
    int j = lane & 31;
    int gw = blockIdx.x * 4 + w;
    const int NW = NBLK * 4;

    float mu = stats2[j] * (1.f / N_NODES);
    float var = stats2[H2 + j] * (1.f / N_NODES) - mu * mu;
    float scale = rsqrtf(var + BN_EPS) * g2[j];
    float shift = beta2[j] - mu * scale;

    float wl0 = W3l[j], wl1 = W3l[H2 + j];
    float wr0 = W3r[j], wr1 = W3r[H2 + j];
    float b0 = b3l[0], b1 = b3l[1];

    for (int p = gw; p < N_NODES / 2; p += NW) {
        int n = p * 2 + h;
        int o0 = off[n], o1 = off[n + 1];
        float sum = 0.f;
        int i = o0;
        for (; i + 16 <= o1; i += 16) {
            int sidx[16];
#pragma unroll
            for (int b = 0; b < 16; ++b) sidx[b] = srt[i + b];
            float v[16];
#pragma unroll
            for (int b = 0; b < 16; ++b) v[b] = bf2f(h2b[(long)sidx[b] * H2 + j]);
#pragma unroll
            for (int b = 0; b < 16; ++b) sum += RELU1(v[b]);
        }
        for (; i + 8 <= o1; i += 8) {
            int sidx[8];
#pragma unroll
            for (int b = 0; b < 8; ++b) sidx[b] = srt[i + b];
            float v[8];
#pragma unroll
            for (int b = 0; b < 8; ++b) v[b] = bf2f(h2b[(long)sidx[b] * H2 + j]);
#pragma unroll
            for (int b = 0; b < 8; ++b) sum += RELU1(v[b]);
        }
        for (; i < o1; ++i) {
            int s = srt[i];
            sum += RELU1(bf2f(h2b[(long)s * H2 + j]));
        }
        float inv = 1.f / (float)max(o1 - o0, 1);
        float meanj = sum * inv;
        float ownj = RELU1(bf2f(h2b[(long)n * H2 + j]));
        float p0 = meanj * wl0 + ownj * wr0;
        float p1 = meanj * wl1 + ownj * wr1;
#pragma unroll
        for (int s = 16; s > 0; s >>= 1) {
            p0 += __shfl_xor(p0, s, 32);
            p1 += __shfl_xor(p1, s, 32);
        }
        if (j == 0) {
            float z0 = p0 + b0, z1 = p1 + b1;
            float m = fmaxf(z0, z1);
            float l = m + logf(__expf(z0 - m) + __expf(z1 - m));
            out[(long)n * 2 + 0] = z0 - l;
            out[(long)n * 2 + 1] = z1 - l;
        }
    }
}

// ---------------- launch ----------------

extern "C" void kernel_launch(void* const* d_in, const int* in_sizes, int n_in,
                              void* d_out, int out_size, void* d_ws, size_t ws_size,
                              hipStream_t stream) {
    const float* x    = (const float*)d_in[0];
    const int*   ei   = (const int*)d_in[1];
    const float* W1l  = (const float*)d_in[2];
    const float* b1l  = (const float*)d_in[3];
    const float* W1r  = (const float*)d_in[4];
    const float* g1   = (const float*)d_in[5];
    const float* bt1  = (const float*)d_in[6];
    const float* W2l  = (const float*)d_in[7];
    const float* b2l  = (const float*)d_in[8];
    const float* W2r  = (const float*)d_in[9];
    const float* g2   = (const float*)d_in[10];
    const float* bt2  = (const float*)d_in[11];
    const float* W3l  = (const float*)d_in[12];
    const float* b3l  = (const float*)d_in[13];
    const float* W3r  = (const float*)d_in[14];
    float* out = (float*)d_out;

    // workspace layout (4B units for ints/floats, then bf16 arrays)
    float* stats1 = (float*)d_ws;            // 128
    float* stats2 = stats1 + 128;            // 64 (+pad to 256)
    int* deg  = (int*)d_ws + 256;            // 100096
    int* off  = deg + 100096;                // 100096 (uses N+1)
    int* cur  = off + 100096;                // 100096
    int* srt  = cur + 100096;                // 1600000
    int* part = srt + 1600000;               // 256
    unsigned short* h1b = (unsigned short*)(part + 256);   // N*64 bf16
    unsigned short* h2b = h1b + (size_t)N_NODES * H1;      // N*32 bf16

    const int* srcv = ei;
    const int* dstv = ei + N_EDGES;

    // zero stats + degree counters
    hipMemsetAsync(d_ws, 0, (256 + 100096) * sizeof(int), stream);

    k_deg   <<<(N_EDGES + 255) / 256, 256, 0, stream>>>(dstv, deg);
    k_scan_a<<<98, 1024, 0, stream>>>(deg, off, part);
    k_scan_b<<<1, 128, 0, stream>>>(part, 98);
    k_scan_c<<<(N_NODES + 255) / 256, 256, 0, stream>>>(off, cur, part);
    k_fill  <<<(N_EDGES + 255) / 256, 256, 0, stream>>>(srcv, dstv, cur, srt);
    k_l1    <<<NBLK, 256, 0, stream>>>(x, off, srt, W1l, b1l, W1r, h1b, stats1);
    k_l2    <<<NBLK, 256, 0, stream>>>(h1b, off, srt, W2l, b2l, W2r, g1, bt1, stats1, h2b, stats2);
    k_l3    <<<NBLK, 256, 0, stream>>>(h2b, off, srt, W3l, b3l, W3r, g2, bt2, stats2, out);
}

// Round 15
// 588.301 us; speedup vs baseline: 1.0841x; 1.0841x over previous
//
#include <hip/hip_runtime.h>
#include <hip/hip_bf16.h>
#include <math.h>

#define N_NODES 100000
#define N_EDGES 1600000
#define F_IN 15
#define H1 64
#define H2 32
#define BN_EPS 1e-5f
#define NBLK 2048            // grid-stride blocks for the layer kernels
#define RELU1(v) fmaxf(fmaf((v), scale, shift), 0.f)

// bf16 storage helpers (RNE)
__device__ __forceinline__ unsigned short f2bf(float f) {
    unsigned u = __float_as_uint(f);
    u += 0x7FFFu + ((u >> 16) & 1u);
    return (unsigned short)(u >> 16);
}
__device__ __forceinline__ float bf2f(unsigned short h) {
    return __uint_as_float(((unsigned)h) << 16);
}
__device__ __forceinline__ float bcast(float v, int k) {  // readlane broadcast
    return __int_as_float(__builtin_amdgcn_readlane(__float_as_int(v), k));
}

// ---------------- CSR build ----------------

__global__ void k_deg(const int* __restrict__ dst, int* __restrict__ deg) {
    int e = blockIdx.x * blockDim.x + threadIdx.x;
    if (e < N_EDGES) atomicAdd(&deg[dst[e]], 1);
}

__global__ void k_scan_a(const int* __restrict__ deg, int* __restrict__ off,
                         int* __restrict__ part) {
    __shared__ int s[1024];
    int i = blockIdx.x * 1024 + threadIdx.x;
    int v = (i < N_NODES) ? deg[i] : 0;
    s[threadIdx.x] = v;
    __syncthreads();
    for (int o = 1; o < 1024; o <<= 1) {
        int t = (threadIdx.x >= o) ? s[threadIdx.x - o] : 0;
        __syncthreads();
        s[threadIdx.x] += t;
        __syncthreads();
    }
    if (i < N_NODES) off[i] = s[threadIdx.x] - v;   // block-local exclusive
    if (threadIdx.x == 1023) part[blockIdx.x] = s[1023];
}

__global__ void k_scan_b(int* __restrict__ part, int nb) {
    __shared__ int s[128];
    int v = (threadIdx.x < nb) ? part[threadIdx.x] : 0;
    s[threadIdx.x] = v;
    __syncthreads();
    for (int o = 1; o < 128; o <<= 1) {
        int t = (threadIdx.x >= o) ? s[threadIdx.x - o] : 0;
        __syncthreads();
        s[threadIdx.x] += t;
        __syncthreads();
    }
    if (threadIdx.x < nb) part[threadIdx.x] = s[threadIdx.x] - v;  // exclusive base
}

__global__ void k_scan_c(int* __restrict__ off, int* __restrict__ cur,
                         const int* __restrict__ part) {
    int i = blockIdx.x * blockDim.x + threadIdx.x;
    if (i < N_NODES) {
        int v = off[i] + part[i >> 10];
        off[i] = v;
        cur[i] = v;
    }
    if (i == 0) off[N_NODES] = N_EDGES;
}

__global__ void k_fill(const int* __restrict__ src, const int* __restrict__ dst,
                       int* __restrict__ cur, int* __restrict__ srt) {
    int e = blockIdx.x * blockDim.x + threadIdx.x;
    if (e < N_EDGES) {
        int p = atomicAdd(&cur[dst[e]], 1);
        srt[p] = src[e];
    }
}

// ---------------- Layer 1: wave-per-node, x gather (4 edges/load) ----------------
// h1_pre = mean(x[nbr])@W1l.T + b1l + x@W1r.T ; bf16 out; fp32 BN stats.

__launch_bounds__(256)
__global__ void k_l1(const float* __restrict__ x, const int* __restrict__ off,
                     const int* __restrict__ srt,
                     const float* __restrict__ W1l, const float* __restrict__ b1l,
                     const float* __restrict__ W1r,
                     unsigned short* __restrict__ h1b, float* __restrict__ stats) {
    __shared__ float m_lds[4][16], o_lds[4][16];
    __shared__ float sred[2 * H1];
    int lane = threadIdx.x & 63;
    int h4 = lane >> 4;          // edge group 0..3
    int k  = lane & 15;          // feature 0..15 (15 used)
    int w = threadIdx.x >> 6;
    int gw = blockIdx.x * 4 + w;
    const int NW = NBLK * 4;

    float wl[F_IN], wr[F_IN];
#pragma unroll
    for (int kk = 0; kk < F_IN; ++kk) {
        wl[kk] = W1l[lane * F_IN + kk];
        wr[kk] = W1r[lane * F_IN + kk];
    }
    float bj = b1l[lane];

    if (threadIdx.x < 2 * H1) sred[threadIdx.x] = 0.f;
    __syncthreads();

    float sS = 0.f, sQ = 0.f;
    for (int n = gw; n < N_NODES; n += NW) {
        int o0 = off[n], o1 = off[n + 1];
        float sum = 0.f;
        int i = o0;
        // 16 edges per batch, 4 edges per load instruction (60/64 lanes active)
        for (; i + 16 <= o1; i += 16) {
            int my = (lane < 16) ? srt[i + lane] : 0;
            float v[4];
#pragma unroll
            for (int b = 0; b < 4; ++b) {
                int s = __shfl(my, b * 4 + h4, 64);   // group h4 takes edge b*4+h4
                v[b] = (k < F_IN) ? x[(long)s * F_IN + k] : 0.f;
            }
            sum += (v[0] + v[1]) + (v[2] + v[3]);
        }
        for (; i < o1; ++i) {     // tail: lanes 0..14 only (one group)
            int s = srt[i];
            if (lane < F_IN) sum += x[(long)s * F_IN + lane];
        }
        // combine the 4 edge groups (feature k aligned across groups)
        sum += __shfl_xor(sum, 16, 64);
        sum += __shfl_xor(sum, 32, 64);
        float inv = 1.f / (float)max(o1 - o0, 1);
        if (lane < F_IN) {
            m_lds[w][lane] = sum * inv;
            o_lds[w][lane] = x[(long)n * F_IN + lane];
        }
        // same-wave LDS write->read (HW-validated)
        float acc = bj;
#pragma unroll
        for (int kk = 0; kk < F_IN; ++kk)
            acc += m_lds[w][kk] * wl[kk] + o_lds[w][kk] * wr[kk];
        h1b[(long)n * H1 + lane] = f2bf(acc);
        sS += acc; sQ += acc * acc;
    }
    atomicAdd(&sred[lane], sS);
    atomicAdd(&sred[H1 + lane], sQ);
    __syncthreads();
    if (threadIdx.x < 2 * H1) atomicAdd(&stats[threadIdx.x], sred[threadIdx.x]);
}

// ---------------- Transform 2: dense, y=relu(bn1(h1)); t2=y@W2l.T ; r2=y@W2r.T+b2l ----
// Register weights (launch_bounds(256,2) so they stay); readlane broadcast GEMM.

__launch_bounds__(256, 2)
__global__ void k_t2(const unsigned short* __restrict__ h1b,
                     const float* __restrict__ W2l, const float* __restrict__ b2l,
                     const float* __restrict__ W2r,
                     const float* __restrict__ g1, const float* __restrict__ beta1,
                     const float* __restrict__ stats1,
                     unsigned short* __restrict__ t2b, float* __restrict__ r2) {
    int lane = threadIdx.x & 63;
    int w = threadIdx.x >> 6;
    int gw = blockIdx.x * 4 + w;
    const int NW = NBLK * 4;

    float mu = stats1[lane] * (1.f / N_NODES);
    float var = stats1[H1 + lane] * (1.f / N_NODES) - mu * mu;
    float scale = rsqrtf(var + BN_EPS) * g1[lane];
    float shift = beta1[lane] - mu * scale;

    const float* wsrc = (lane < H2) ? (W2l + lane * H1) : (W2r + (lane - H2) * H1);
    float wreg[H1];
#pragma unroll
    for (int kk = 0; kk < H1; ++kk) wreg[kk] = wsrc[kk];
    float addc = (lane < H2) ? 0.f : b2l[lane - H2];

    for (int n = gw; n < N_NODES; n += NW) {
        float y = RELU1(bf2f(h1b[(long)n * H1 + lane]));   // feature = lane
        float acc = addc;
#pragma unroll
        for (int kk = 0; kk < H1; ++kk)
            acc = fmaf(bcast(y, kk), wreg[kk], acc);
        if (lane < H2) t2b[(long)n * H2 + lane] = f2bf(acc);
        else           r2[(long)n * H2 + (lane - H2)] = acc;
    }
}

// ---------------- Aggregate 2: wave-per-node, sum t2 rows (2 edges/load) -------------
// h2_pre = mean(t2[nbr]) + r2 ; fp32 out; BN2 stats.

__launch_bounds__(256)
__global__ void k_a2(const unsigned short* __restrict__ t2b, const float* __restrict__ r2,
                     const int* __restrict__ off, const int* __restrict__ srt,
                     float* __restrict__ h2p, float* __restrict__ stats2) {
    __shared__ float sred[2 * H2];
    int lane = threadIdx.x & 63;
    int j = lane & 31;
    int h = lane >> 5;
    int w = threadIdx.x >> 6;
    int gw = blockIdx.x * 4 + w;
    const int NW = NBLK * 4;

    if (threadIdx.x < 2 * H2) sred[threadIdx.x] = 0.f;
    __syncthreads();

    float sS = 0.f, sQ = 0.f;
    for (int n = gw; n < N_NODES; n += NW) {
        int o0 = off[n], o1 = off[n + 1];
        float sum = 0.f;
        int i = o0;
        for (; i + 16 <= o1; i += 16) {
            int my = (lane < 16) ? srt[i + lane] : 0;
            float v[8];
#pragma unroll
            for (int b = 0; b < 8; ++b) {
                int s0 = __shfl(my, 2 * b, 64);
                int s1 = __shfl(my, 2 * b + 1, 64);
                int s = h ? s1 : s0;
                v[b] = bf2f(t2b[(long)s * H2 + j]);
            }
            sum += (((v[0]+v[1])+(v[2]+v[3])) + ((v[4]+v[5])+(v[6]+v[7])));
        }
        for (; i + 2 <= o1; i += 2) {      // pair tail
            int s0 = srt[i], s1 = srt[i + 1];
            int s = h ? s1 : s0;
            sum += bf2f(t2b[(long)s * H2 + j]);
        }
        if (i < o1) {                      // single tail -> half 0 only
            int s = srt[i];
            if (!h) sum += bf2f(t2b[(long)s * H2 + j]);
        }
        sum += __shfl_xor(sum, 32, 64);    // combine the two halves
        float inv = 1.f / (float)max(o1 - o0, 1);
        if (lane < H2) {
            float hp = fmaf(sum, inv, r2[(long)n * H2 + j]);
            h2p[(long)n * H2 + j] = hp;
            sS += hp; sQ += hp * hp;
        }
    }
    if (lane < H2) {
        atomicAdd(&sred[j], sS);
        atomicAdd(&sred[H2 + j], sQ);
    }
    __syncthreads();
    if (threadIdx.x < 2 * H2) atomicAdd(&stats2[threadIdx.x], sred[threadIdx.x]);
}

// ---------------- Transform 3: y2=relu(bn2(h2p)); t3=y2@W3l.T ; r3=y2@W3r.T+b3l ------

__launch_bounds__(256)
__global__ void k_t3(const float* __restrict__ h2p,
                     const float* __restrict__ W3l, const float* __restrict__ b3l,
                     const float* __restrict__ W3r,
                     const float* __restrict__ g2, const float* __restrict__ beta2,
                     const float* __restrict__ stats2,
                     float* __restrict__ t3, float* __restrict__ r3) {
    int lane = threadIdx.x & 63;
    int j = lane & 31;
    int h = lane >> 5;
    int w = threadIdx.x >> 6;
    int gw = blockIdx.x * 4 + w;
    const int NW = NBLK * 4;

    float mu = stats2[j] * (1.f / N_NODES);
    float var = stats2[H2 + j] * (1.f / N_NODES) - mu * mu;
    float scale = rsqrtf(var + BN_EPS) * g2[j];
    float shift = beta2[j] - mu * scale;

    float wl0 = W3l[j], wl1 = W3l[H2 + j];
    float wr0 = W3r[j], wr1 = W3r[H2 + j];
    float b0 = b3l[0], b1 = b3l[1];

    for (int p = gw; p < N_NODES / 2; p += NW) {
        int n = p * 2 + h;
        float y = RELU1(h2p[(long)n * H2 + j]);
        float p0 = y * wl0, p1 = y * wl1, q0 = y * wr0, q1 = y * wr1;
#pragma unroll
        for (int s = 16; s > 0; s >>= 1) {
            p0 += __shfl_xor(p0, s, 32);
            p1 += __shfl_xor(p1, s, 32);
            q0 += __shfl_xor(q0, s, 32);
            q1 += __shfl_xor(q1, s, 32);
        }
        if (j == 0) {
            *(float2*)(t3 + (long)n * 2) = make_float2(p0, p1);
            *(float2*)(r3 + (long)n * 2) = make_float2(q0 + b0, q1 + b1);
        }
    }
}

// ---------------- Aggregate 3: thread-per-node, t3 gather (8B/edge), log_softmax -----

__launch_bounds__(256)
__global__ void k_a3(const float* __restrict__ t3, const float* __restrict__ r3,
                     const int* __restrict__ off, const int* __restrict__ srt,
                     float* __restrict__ out) {
    int n = blockIdx.x * 256 + threadIdx.x;
    if (n >= N_NODES) return;
    int o0 = off[n], o1 = off[n + 1];
    float s0 = 0.f, s1 = 0.f;
    int i = o0;
    for (; i + 8 <= o1; i += 8) {
        int sidx[8];
#pragma unroll
        for (int b = 0; b < 8; ++b) sidx[b] = srt[i + b];
        float2 v[8];
#pragma unroll
        for (int b = 0; b < 8; ++b) v[b] = *(const float2*)(t3 + (long)sidx[b] * 2);
#pragma unroll
        for (int b = 0; b < 8; ++b) { s0 += v[b].x; s1 += v[b].y; }
    }
    for (; i < o1; ++i) {
        float2 v = *(const float2*)(t3 + (long)srt[i] * 2);
        s0 += v.x; s1 += v.y;
    }
    float inv = 1.f / (float)max(o1 - o0, 1);
    float2 rr = *(const float2*)(r3 + (long)n * 2);
    float z0 = fmaf(s0, inv, rr.x);
    float z1 = fmaf(s1, inv, rr.y);
    float m = fmaxf(z0, z1);
    float l = m + logf(__expf(z0 - m) + __expf(z1 - m));
    out[(long)n * 2 + 0] = z0 - l;
    out[(long)n * 2 + 1] = z1 - l;
}

// ---------------- launch ----------------

extern "C" void kernel_launch(void* const* d_in, const int* in_sizes, int n_in,
                              void* d_out, int out_size, void* d_ws, size_t ws_size,
                              hipStream_t stream) {
    const float* x    = (const float*)d_in[0];
    const int*   ei   = (const int*)d_in[1];
    const float* W1l  = (const float*)d_in[2];
    const float* b1l  = (const float*)d_in[3];
    const float* W1r  = (const float*)d_in[4];
    const float* g1   = (const float*)d_in[5];
    const float* bt1  = (const float*)d_in[6];
    const float* W2l  = (const float*)d_in[7];
    const float* b2l  = (const float*)d_in[8];
    const float* W2r  = (const float*)d_in[9];
    const float* g2   = (const float*)d_in[10];
    const float* bt2  = (const float*)d_in[11];
    const float* W3l  = (const float*)d_in[12];
    const float* b3l  = (const float*)d_in[13];
    const float* W3r  = (const float*)d_in[14];
    float* out = (float*)d_out;

    // workspace layout (4B units) — total ~41 MB (< proven 46 MB footprint)
    float* stats1 = (float*)d_ws;                          // 128
    float* stats2 = stats1 + 128;                          // 64 (+pad to 256)
    int* deg  = (int*)d_ws + 256;                          // 100096
    int* off  = deg + 100096;                              // 100096 (N+1 used)
    int* cur  = off + 100096;                              // 100096
    int* srt  = cur + 100096;                              // 1600000
    int* part = srt + 1600000;                             // 256
    unsigned short* h1b = (unsigned short*)(part + 256);   // N*64 bf16 (3.2M units)
    float* h2p = (float*)h1b;                              // N*32 f32 — reuses h1b (dead after k_t2)
    unsigned short* t2b = (unsigned short*)((int*)(part + 256) + 3200000);  // N*32 bf16 (1.6M units)
    float* r2 = (float*)((int*)(part + 256) + 3200000 + 1600000);           // N*32 f32 (3.2M units)
    float* t3 = r2 + 3200000;                              // N*2 f32 (200k units)
    float* r3 = t3 + 200000;                               // N*2 f32 (200k units)

    const int* srcv = ei;
    const int* dstv = ei + N_EDGES;

    // zero stats + degree counters
    hipMemsetAsync(d_ws, 0, (256 + 100096) * sizeof(int), stream);

    k_deg   <<<(N_EDGES + 255) / 256, 256, 0, stream>>>(dstv, deg);
    k_scan_a<<<98, 1024, 0, stream>>>(deg, off, part);
    k_scan_b<<<1, 128, 0, stream>>>(part, 98);
    k_scan_c<<<(N_NODES + 255) / 256, 256, 0, stream>>>(off, cur, part);
    k_fill  <<<(N_EDGES + 255) / 256, 256, 0, stream>>>(srcv, dstv, cur, srt);
    k_l1    <<<NBLK, 256, 0, stream>>>(x, off, srt, W1l, b1l, W1r, h1b, stats1);
    k_t2    <<<NBLK, 256, 0, stream>>>(h1b, W2l, b2l, W2r, g1, bt1, stats1, t2b, r2);
    k_a2    <<<NBLK, 256, 0, stream>>>(t2b, r2, off, srt, h2p, stats2);
    k_t3    <<<NBLK, 256, 0, stream>>>(h2p, W3l, b3l, W3r, g2, bt2, stats2, t3, r3);
    k_a3    <<<(N_NODES + 255) / 256, 256, 0, stream>>>(t3, r3, off, srt, out);
}

// Round 16
// 570.038 us; speedup vs baseline: 1.1188x; 1.0320x over previous
//
#include <hip/hip_runtime.h>
#include <hip/hip_bf16.h>
#include <math.h>

#define N_NODES 100000
#define N_EDGES 1600000
#define F_IN 15
#define H1 64
#define H2 32
#define BN_EPS 1e-5f
#define NBLK 2048
#define SRT_CAP 1900032      // >= E + 3*N (deg padded to multiple of 4)
#define RELU1(v) fmaxf(fmaf((v), scale, shift), 0.f)

// bf16 storage helpers (RNE)
__device__ __forceinline__ unsigned short f2bf(float f) {
    unsigned u = __float_as_uint(f);
    u += 0x7FFFu + ((u >> 16) & 1u);
    return (unsigned short)(u >> 16);
}
__device__ __forceinline__ float bf2f(unsigned short h) {
    return __uint_as_float(((unsigned)h) << 16);
}
__device__ __forceinline__ float bcast(float v, int k) {
    return __int_as_float(__builtin_amdgcn_readlane(__float_as_int(v), k));
}

// ---------------- CSR build (padded to multiple of 4, sentinel -1) ----------------

__global__ void k_deg(const int* __restrict__ dst, int* __restrict__ deg) {
    int e = blockIdx.x * blockDim.x + threadIdx.x;
    if (e < N_EDGES) atomicAdd(&deg[dst[e]], 1);
}

__global__ void k_scan_a(const int* __restrict__ deg, int* __restrict__ off,
                         int* __restrict__ part) {
    __shared__ int s[1024];
    int i = blockIdx.x * 1024 + threadIdx.x;
    int d = (i < N_NODES) ? deg[i] : 0;
    int v = (d + 3) & ~3;                 // padded degree
    s[threadIdx.x] = v;
    __syncthreads();
    for (int o = 1; o < 1024; o <<= 1) {
        int t = (threadIdx.x >= o) ? s[threadIdx.x - o] : 0;
        __syncthreads();
        s[threadIdx.x] += t;
        __syncthreads();
    }
    if (i < N_NODES) off[i] = s[threadIdx.x] - v;   // block-local exclusive
    if (threadIdx.x == 1023) part[blockIdx.x] = s[1023];
}

__global__ void k_scan_b(int* __restrict__ part, int nb) {
    __shared__ int s[128];
    int v = (threadIdx.x < nb) ? part[threadIdx.x] : 0;
    s[threadIdx.x] = v;
    __syncthreads();
    for (int o = 1; o < 128; o <<= 1) {
        int t = (threadIdx.x >= o) ? s[threadIdx.x - o] : 0;
        __syncthreads();
        s[threadIdx.x] += t;
        __syncthreads();
    }
    if (threadIdx.x < nb) part[threadIdx.x] = s[threadIdx.x] - v;
}

__global__ void k_scan_c(int* __restrict__ off, int* __restrict__ cur,
                         const int* __restrict__ part, const int* __restrict__ deg) {
    int i = blockIdx.x * blockDim.x + threadIdx.x;
    if (i < N_NODES) {
        int v = off[i] + part[i >> 10];
        off[i] = v;
        cur[i] = v;
        if (i == N_NODES - 1) off[N_NODES] = v + ((deg[i] + 3) & ~3);
    }
}

__global__ void k_fill(const int* __restrict__ src, const int* __restrict__ dst,
                       int* __restrict__ cur, int* __restrict__ srt) {
    int e = blockIdx.x * blockDim.x + threadIdx.x;
    if (e < N_EDGES) {
        int p = atomicAdd(&cur[dst[e]], 1);
        srt[p] = src[e];
    }
}

// ---------------- Layer 1: wave-per-node, direct 4-group x gather, no serial tail ----

__launch_bounds__(256)
__global__ void k_l1(const float* __restrict__ x, const int* __restrict__ off,
                     const int* __restrict__ srt, const int* __restrict__ deg,
                     const float* __restrict__ W1l, const float* __restrict__ b1l,
                     const float* __restrict__ W1r,
                     unsigned short* __restrict__ h1b, float* __restrict__ stats) {
    __shared__ float m_lds[4][16], o_lds[4][16];
    __shared__ float sred[2 * H1];
    int lane = threadIdx.x & 63;
    int h4 = lane >> 4;          // edge group 0..3
    int k  = lane & 15;          // feature 0..15 (15 used)
    int w = threadIdx.x >> 6;
    int gw = blockIdx.x * 4 + w;
    const int NW = NBLK * 4;

    float wl[F_IN], wr[F_IN];
#pragma unroll
    for (int kk = 0; kk < F_IN; ++kk) {
        wl[kk] = W1l[lane * F_IN + kk];
        wr[kk] = W1r[lane * F_IN + kk];
    }
    float bj = b1l[lane];

    if (threadIdx.x < 2 * H1) sred[threadIdx.x] = 0.f;
    __syncthreads();

    float sS = 0.f, sQ = 0.f;
    for (int n = gw; n < N_NODES; n += NW) {
        int o0 = off[n], o1 = off[n + 1];   // padded bounds (multiple of 4)
        int dg = deg[n];
        float sum = 0.f;
        int i = o0;
        // 16 edges per unrolled iter: 4 independent (srt -> x) chains
        for (; i + 16 <= o1; i += 16) {
            int s0 = srt[i + h4], s1 = srt[i + 4 + h4],
                s2 = srt[i + 8 + h4], s3 = srt[i + 12 + h4];
            float v0 = (s0 >= 0 && k < F_IN) ? x[(long)s0 * F_IN + k] : 0.f;
            float v1 = (s1 >= 0 && k < F_IN) ? x[(long)s1 * F_IN + k] : 0.f;
            float v2 = (s2 >= 0 && k < F_IN) ? x[(long)s2 * F_IN + k] : 0.f;
            float v3 = (s3 >= 0 && k < F_IN) ? x[(long)s3 * F_IN + k] : 0.f;
            sum += (v0 + v1) + (v2 + v3);
        }
        // remaining 0..3 quad rounds (padded -> no per-edge tail)
        for (; i < o1; i += 4) {
            int s = srt[i + h4];
            sum += (s >= 0 && k < F_IN) ? x[(long)s * F_IN + k] : 0.f;
        }
        sum += __shfl_xor(sum, 16, 64);
        sum += __shfl_xor(sum, 32, 64);
        float inv = 1.f / (float)max(dg, 1);
        if (lane < F_IN) {
            m_lds[w][lane] = sum * inv;
            o_lds[w][lane] = x[(long)n * F_IN + lane];
        }
        // same-wave LDS write->read (HW-validated)
        float acc = bj;
#pragma unroll
        for (int kk = 0; kk < F_IN; ++kk)
            acc += m_lds[w][kk] * wl[kk] + o_lds[w][kk] * wr[kk];
        h1b[(long)n * H1 + lane] = f2bf(acc);
        sS += acc; sQ += acc * acc;
    }
    atomicAdd(&sred[lane], sS);
    atomicAdd(&sred[H1 + lane], sQ);
    __syncthreads();
    if (threadIdx.x < 2 * H1) atomicAdd(&stats[threadIdx.x], sred[threadIdx.x]);
}

// ---------------- Transform 2: y=relu(bn1(h1)); t2=y@W2l.T ; r2=y@W2r.T+b2l ----------

__launch_bounds__(256, 2)
__global__ void k_t2(const unsigned short* __restrict__ h1b,
                     const float* __restrict__ W2l, const float* __restrict__ b2l,
                     const float* __restrict__ W2r,
                     const float* __restrict__ g1, const float* __restrict__ beta1,
                     const float* __restrict__ stats1,
                     unsigned short* __restrict__ t2b, float* __restrict__ r2) {
    int lane = threadIdx.x & 63;
    int w = threadIdx.x >> 6;
    int gw = blockIdx.x * 4 + w;
    const int NW = NBLK * 4;

    float mu = stats1[lane] * (1.f / N_NODES);
    float var = stats1[H1 + lane] * (1.f / N_NODES) - mu * mu;
    float scale = rsqrtf(var + BN_EPS) * g1[lane];
    float shift = beta1[lane] - mu * scale;

    const float* wsrc = (lane < H2) ? (W2l + lane * H1) : (W2r + (lane - H2) * H1);
    float wreg[H1];
#pragma unroll
    for (int kk = 0; kk < H1; ++kk) wreg[kk] = wsrc[kk];
    float addc = (lane < H2) ? 0.f : b2l[lane - H2];

    for (int n = gw; n < N_NODES; n += NW) {
        float y = RELU1(bf2f(h1b[(long)n * H1 + lane]));
        float acc = addc;
#pragma unroll
        for (int kk = 0; kk < H1; ++kk)
            acc = fmaf(bcast(y, kk), wreg[kk], acc);
        if (lane < H2) t2b[(long)n * H2 + lane] = f2bf(acc);
        else           r2[(long)n * H2 + (lane - H2)] = acc;
    }
}

// ---------------- Aggregate 2: wave-per-node, direct 2-edge loads, no serial tail ----

__launch_bounds__(256)
__global__ void k_a2(const unsigned short* __restrict__ t2b, const float* __restrict__ r2,
                     const int* __restrict__ off, const int* __restrict__ srt,
                     const int* __restrict__ deg,
                     float* __restrict__ h2p, float* __restrict__ stats2) {
    __shared__ float sred[2 * H2];
    int lane = threadIdx.x & 63;
    int j = lane & 31;
    int h = lane >> 5;
    int w = threadIdx.x >> 6;
    int gw = blockIdx.x * 4 + w;
    const int NW = NBLK * 4;

    if (threadIdx.x < 2 * H2) sred[threadIdx.x] = 0.f;
    __syncthreads();

    float sS = 0.f, sQ = 0.f;
    for (int n = gw; n < N_NODES; n += NW) {
        int o0 = off[n], o1 = off[n + 1];   // padded (multiple of 4)
        int dg = deg[n];
        float sum = 0.f;
        int i = o0;
        for (; i + 16 <= o1; i += 16) {     // 8 independent 2-edge chains
            float v[8];
#pragma unroll
            for (int b = 0; b < 8; ++b) {
                int s = srt[i + 2 * b + h];
                v[b] = (s >= 0) ? bf2f(t2b[(long)s * H2 + j]) : 0.f;
            }
            sum += (((v[0]+v[1])+(v[2]+v[3])) + ((v[4]+v[5])+(v[6]+v[7])));
        }
        for (; i < o1; i += 4) {            // 0..3 quad rounds, 2 chains each
            int s0 = srt[i + h], s1 = srt[i + 2 + h];
            float u0 = (s0 >= 0) ? bf2f(t2b[(long)s0 * H2 + j]) : 0.f;
            float u1 = (s1 >= 0) ? bf2f(t2b[(long)s1 * H2 + j]) : 0.f;
            sum += u0 + u1;
        }
        sum += __shfl_xor(sum, 32, 64);
        float inv = 1.f / (float)max(dg, 1);
        if (lane < H2) {
            float hp = fmaf(sum, inv, r2[(long)n * H2 + j]);
            h2p[(long)n * H2 + j] = hp;
            sS += hp; sQ += hp * hp;
        }
    }
    if (lane < H2) {
        atomicAdd(&sred[j], sS);
        atomicAdd(&sred[H2 + j], sQ);
    }
    __syncthreads();
    if (threadIdx.x < 2 * H2) atomicAdd(&stats2[threadIdx.x], sred[threadIdx.x]);
}

// ---------------- Transform 3 ----------------

__launch_bounds__(256)
__global__ void k_t3(const float* __restrict__ h2p,
                     const float* __restrict__ W3l, const float* __restrict__ b3l,
                     const float* __restrict__ W3r,
                     const float* __restrict__ g2, const float* __restrict__ beta2,
                     const float* __restrict__ stats2,
                     float* __restrict__ t3, float* __restrict__ r3) {
    int lane = threadIdx.x & 63;
    int j = lane & 31;
    int h = lane >> 5;
    int w = threadIdx.x >> 6;
    int gw = blockIdx.x * 4 + w;
    const int NW = NBLK * 4;

    float mu = stats2[j] * (1.f / N_NODES);
    float var = stats2[H2 + j] * (1.f / N_NODES) - mu * mu;
    float scale = rsqrtf(var + BN_EPS) * g2[j];
    float shift = beta2[j] - mu * scale;

    float wl0 = W3l[j], wl1 = W3l[H2 + j];
    float wr0 = W3r[j], wr1 = W3r[H2 + j];
    float b0 = b3l[0], b1 = b3l[1];

    for (int p = gw; p < N_NODES / 2; p += NW) {
        int n = p * 2 + h;
        float y = RELU1(h2p[(long)n * H2 + j]);
        float p0 = y * wl0, p1 = y * wl1, q0 = y * wr0, q1 = y * wr1;
#pragma unroll
        for (int s = 16; s > 0; s >>= 1) {
            p0 += __shfl_xor(p0, s, 32);
            p1 += __shfl_xor(p1, s, 32);
            q0 += __shfl_xor(q0, s, 32);
            q1 += __shfl_xor(q1, s, 32);
        }
        if (j == 0) {
            *(float2*)(t3 + (long)n * 2) = make_float2(p0, p1);
            *(float2*)(r3 + (long)n * 2) = make_float2(q0 + b0, q1 + b1);
        }
    }
}

// ---------------- Aggregate 3: thread-per-node, padded batches, log_softmax ----------

__launch_bounds__(256)
__global__ void k_a3(const float* __restrict__ t3, const float* __restrict__ r3,
                     const int* __restrict__ off, const int* __restrict__ srt,
                     const int* __restrict__ deg, float* __restrict__ out) {
    int n = blockIdx.x * 256 + threadIdx.x;
    if (n >= N_NODES) return;
    int o0 = off[n], o1 = off[n + 1];       // padded
    int dg = deg[n];
    float s0 = 0.f, s1 = 0.f;
    int i = o0;
    for (; i + 8 <= o1; i += 8) {
        int sx[8];
#pragma unroll
        for (int b = 0; b < 8; ++b) sx[b] = srt[i + b];
#pragma unroll
        for (int b = 0; b < 8; ++b) {
            if (sx[b] >= 0) {
                float2 v = *(const float2*)(t3 + (long)sx[b] * 2);
                s0 += v.x; s1 += v.y;
            }
        }
    }
    for (; i < o1; i += 4) {
        int sx[4];
#pragma unroll
        for (int b = 0; b < 4; ++b) sx[b] = srt[i + b];
#pragma unroll
        for (int b = 0; b < 4; ++b) {
            if (sx[b] >= 0) {
                float2 v = *(const float2*)(t3 + (long)sx[b] * 2);
                s0 += v.x; s1 += v.y;
            }
        }
    }
    float inv = 1.f / (float)max(dg, 1);
    float2 rr = *(const float2*)(r3 + (long)n * 2);
    float z0 = fmaf(s0, inv, rr.x);
    float z1 = fmaf(s1, inv, rr.y);
    float m = fmaxf(z0, z1);
    float l = m + logf(__expf(z0 - m) + __expf(z1 - m));
    out[(long)n * 2 + 0] = z0 - l;
    out[(long)n * 2 + 1] = z1 - l;
}

// ---------------- launch ----------------

extern "C" void kernel_launch(void* const* d_in, const int* in_sizes, int n_in,
                              void* d_out, int out_size, void* d_ws, size_t ws_size,
                              hipStream_t stream) {
    const float* x    = (const float*)d_in[0];
    const int*   ei   = (const int*)d_in[1];
    const float* W1l  = (const float*)d_in[2];
    const float* b1l  = (const float*)d_in[3];
    const float* W1r  = (const float*)d_in[4];
    const float* g1   = (const float*)d_in[5];
    const float* bt1  = (const float*)d_in[6];
    const float* W2l  = (const float*)d_in[7];
    const float* b2l  = (const float*)d_in[8];
    const float* W2r  = (const float*)d_in[9];
    const float* g2   = (const float*)d_in[10];
    const float* bt2  = (const float*)d_in[11];
    const float* W3l  = (const float*)d_in[12];
    const float* b3l  = (const float*)d_in[13];
    const float* W3r  = (const float*)d_in[14];
    float* out = (float*)d_out;

    // workspace layout (4B units) — total ~42.4 MB
    float* stats1 = (float*)d_ws;                          // [0,128)
    float* stats2 = stats1 + 128;                          // [128,192) (+pad to 256)
    int* deg  = (int*)d_ws + 256;                          // [256, 100352)
    int* off  = deg + 100096;                              // [100352, 200448) (N+1 used)
    int* cur  = off + 100096;                              // [200448, 300544)
    int* srt  = cur + 100096;                              // [300544, +SRT_CAP)
    int* part = srt + SRT_CAP;                             // 256
    unsigned short* h1b = (unsigned short*)(part + 256);   // N*64 bf16 (3.2M ints)
    float* h2p = (float*)h1b;                              // N*32 f32 — overlays h1b (dead after k_t2)
    unsigned short* t2b = (unsigned short*)((int*)(part + 256) + 3200000);  // N*32 bf16
    float* r2 = (float*)((int*)(part + 256) + 3200000 + 1600000);           // N*32 f32
    float* t3 = r2 + 3200000;                              // N*2 f32
    float* r3 = t3 + 200000;                               // N*2 f32

    const int* srcv = ei;
    const int* dstv = ei + N_EDGES;

    // zero stats + degree counters; fill srt with sentinel 0xFFFFFFFF (-1)
    hipMemsetAsync(d_ws, 0, (256 + 100096) * sizeof(int), stream);
    hipMemsetAsync(srt, 0xFF, (size_t)SRT_CAP * sizeof(int), stream);

    k_deg   <<<(N_EDGES + 255) / 256, 256, 0, stream>>>(dstv, deg);
    k_scan_a<<<98, 1024, 0, stream>>>(deg, off, part);
    k_scan_b<<<1, 128, 0, stream>>>(part, 98);
    k_scan_c<<<(N_NODES + 255) / 256, 256, 0, stream>>>(off, cur, part, deg);
    k_fill  <<<(N_EDGES + 255) / 256, 256, 0, stream>>>(srcv, dstv, cur, srt);
    k_l1    <<<NBLK, 256, 0, stream>>>(x, off, srt, deg, W1l, b1l, W1r, h1b, stats1);
    k_t2    <<<NBLK, 256, 0, stream>>>(h1b, W2l, b2l, W2r, g1, bt1, stats1, t2b, r2);
    k_a2    <<<NBLK, 256, 0, stream>>>(t2b, r2, off, srt, deg, h2p, stats2);
    k_t3    <<<NBLK, 256, 0, stream>>>(h2p, W3l, b3l, W3r, g2, bt2, stats2, t3, r3);
    k_a3    <<<(N_NODES + 255) / 256, 256, 0, stream>>>(t3, r3, off, srt, deg, out);
}